// Round 16
// baseline (149.199 us; speedup 1.0000x reference)
//
#include <hip/hip_runtime.h>

#define N_NODES 100000
#define F_FRAG  16384
#define D_DANG  8192
#define E_EDGE  4096
#define EMB     300
#define EMB2    90000   // EMB*EMB
#define EMB4    75      // EMB/4
#define EMBP    150     // EMB/2 (bf16 d-pairs)
#define DCH     100     // d-chunk for edge gemm (3 chunks)
#define DCH4    25      // DCH/4

// ---------------- init ----------------
__global__ void init_meta(int* hist, int* remap, int* n_needed) {
    int i = blockIdx.x * blockDim.x + threadIdx.x;
    if (i < F_FRAG) { hist[i] = 0; remap[i] = -1; }
    if (i == 0) *n_needed = 0;
}

__global__ void mark_needed(const int* __restrict__ dangling_idx,
                            const int* __restrict__ frag_batch,
                            int* __restrict__ remap, int* __restrict__ n_needed) {
    int i = blockIdx.x * blockDim.x + threadIdx.x;
    if (i >= D_DANG) return;
    int f = frag_batch[dangling_idx[i]];
    if (atomicCAS(&remap[f], -1, -2) == -1)
        remap[f] = atomicAdd(n_needed, 1);
}

// ---------------- counting sort of nodes by fragment ----------------
__global__ void node_hist(const int* __restrict__ frag_batch, int* __restrict__ hist) {
    int i = blockIdx.x * blockDim.x + threadIdx.x;
    if (i < N_NODES) atomicAdd(&hist[frag_batch[i]], 1);
}

__global__ __launch_bounds__(256) void scan_hist(const int* __restrict__ hist,
                                                 int* __restrict__ offs,
                                                 int* __restrict__ cur) {
    __shared__ int part[256];
    __shared__ int pref[257];
    int t = threadIdx.x;
    int base = t * 64;
    int s = 0;
    for (int j = 0; j < 64; ++j) s += hist[base + j];
    part[t] = s;
    __syncthreads();
    if (t == 0) {
        pref[0] = 0;
        for (int i = 0; i < 256; ++i) pref[i + 1] = pref[i] + part[i];
    }
    __syncthreads();
    int run = pref[t];
    for (int j = 0; j < 64; ++j) {
        offs[base + j] = run;
        cur[base + j]  = run;
        run += hist[base + j];
    }
}

__global__ void scatter_nodes(const int* __restrict__ frag_batch,
                              const int* __restrict__ remap,
                              int* __restrict__ cur, int* __restrict__ node_list) {
    int i = blockIdx.x * blockDim.x + threadIdx.x;
    if (i >= N_NODES) return;
    int f = frag_batch[i];
    if (remap[f] < 0) return;
    int p = atomicAdd(&cur[f], 1);
    node_list[p] = i;
}

// one wave per needed fragment, full 300-col row; writes MEAN (compacted)
__global__ __launch_bounds__(256) void gather_mean(
    const float* __restrict__ out, const int* __restrict__ remap,
    const int* __restrict__ hist, const int* __restrict__ offs,
    const int* __restrict__ node_list, float* __restrict__ fmean) {
    int wid = blockIdx.x * 4 + (threadIdx.x >> 6);
    if (wid >= F_FRAG) return;
    int cid = remap[wid];
    if (cid < 0) return;
    int lane = threadIdx.x & 63;
    int cnt = hist[wid], off = offs[wid];
    float acc[5] = {0.f, 0.f, 0.f, 0.f, 0.f};
    int n = 0;
    for (; n + 1 < cnt; n += 2) {
        const float* r0 = out + (size_t)node_list[off + n] * EMB;
        const float* r1 = out + (size_t)node_list[off + n + 1] * EMB;
#pragma unroll
        for (int j = 0; j < 5; ++j) {
            int k = lane + 64 * j;
            if (k < EMB) acc[j] += r0[k] + r1[k];
        }
    }
    if (n < cnt) {
        const float* r0 = out + (size_t)node_list[off + n] * EMB;
#pragma unroll
        for (int j = 0; j < 5; ++j) {
            int k = lane + 64 * j;
            if (k < EMB) acc[j] += r0[k];
        }
    }
    float inv = 1.0f / fmaxf((float)cnt, 1.0f);
#pragma unroll
    for (int j = 0; j < 5; ++j) {
        int k = lane + 64 * j;
        if (k < EMB) fmean[(size_t)cid * EMB + k] = acc[j] * inv;
    }
}

// ---------------- W -> bf16 pair pack: Wp16[p*EMB+k] = {bf16 W[2p][k], bf16 W[2p+1][k]} ----------------
__global__ void pack_w16(const float* __restrict__ W, unsigned* __restrict__ Wp16) {
    int i = blockIdx.x * blockDim.x + threadIdx.x;
    if (i >= EMBP * EMB) return;
    int p = i / EMB, k = i - p * EMB;
    unsigned x0 = __float_as_uint(W[(size_t)(2 * p) * EMB + k]);
    unsigned x1 = __float_as_uint(W[(size_t)(2 * p + 1) * EMB + k]);
    unsigned r0 = (x0 + 0x7fffu + ((x0 >> 16) & 1u)) >> 16;   // RNE bf16
    unsigned r1 = (x1 + 0x7fffu + ((x1 >> 16) & 1u)) >> 16;
    Wp16[i] = r0 | (r1 << 16);
}

// ---------------- projection: h = out[didx] @ W + b + fmean ----------------
// R12 winning shape (32 rows, 512 thr, 4r x 5c, x2 unroll); W as bf16 pairs:
// halves W load instructions AND L1 bytes; unpack = 1 shift/and per weight.
__global__ __launch_bounds__(512) void proj_kernel(
    const float* __restrict__ out, const int* __restrict__ dangling_idx,
    const int* __restrict__ frag_batch, const int* __restrict__ remap,
    const unsigned* __restrict__ Wp16, const float* __restrict__ b,
    const float* __restrict__ fmean, float* __restrict__ h) {
    __shared__ float rows[32][EMB];
    __shared__ int gidx[32], cids[32];
    int base = blockIdx.x * 32;
    if (threadIdx.x < 32) {
        int gi = dangling_idx[base + threadIdx.x];
        gidx[threadIdx.x] = gi;
        cids[threadIdx.x] = remap[frag_batch[gi]];
    }
    __syncthreads();
    {
        float4* dst = (float4*)&rows[0][0];
        for (int j = threadIdx.x; j < 32 * EMB4; j += 512) {
            int r = j / EMB4, col = j - r * EMB4;
            dst[j] = ((const float4*)(out + (size_t)gidx[r] * EMB))[col];
        }
    }
    __syncthreads();
    int lane = threadIdx.x & 63;
    int wv   = threadIdx.x >> 6;   // 0..7, each wave owns 4 rows
    bool k4ok = (lane + 256 < EMB);
    float acc[4][5];
#pragma unroll
    for (int i = 0; i < 4; ++i)
#pragma unroll
        for (int j = 0; j < 5; ++j) acc[i][j] = 0.f;

    int d = 0;
    for (; d + 8 <= EMB; d += 8) {
        int p0 = d >> 1;
        unsigned up[4][5];
#pragma unroll
        for (int tp = 0; tp < 4; ++tp) {
            const unsigned* Wr = Wp16 + (size_t)(p0 + tp) * EMB + lane;
#pragma unroll
            for (int j = 0; j < 5; ++j)
                up[tp][j] = (j < 4 || k4ok) ? Wr[64 * j] : 0u;
        }
        float w[8][5];
#pragma unroll
        for (int tp = 0; tp < 4; ++tp)
#pragma unroll
            for (int j = 0; j < 5; ++j) {
                w[2 * tp][j]     = __uint_as_float(up[tp][j] << 16);
                w[2 * tp + 1][j] = __uint_as_float(up[tp][j] & 0xffff0000u);
            }
#pragma unroll
        for (int i = 0; i < 4; ++i) {
            float4 hv0 = *(const float4*)&rows[wv * 4 + i][d];
            float4 hv1 = *(const float4*)&rows[wv * 4 + i][d + 4];
#pragma unroll
            for (int j = 0; j < 5; ++j)
                acc[i][j] += hv0.x * w[0][j] + hv0.y * w[1][j] +
                             hv0.z * w[2][j] + hv0.w * w[3][j] +
                             hv1.x * w[4][j] + hv1.y * w[5][j] +
                             hv1.z * w[6][j] + hv1.w * w[7][j];
        }
    }
    {   // tail: 4 remaining d-values (300 = 8*37 + 4) = 2 pairs
        int p0 = d >> 1;
        unsigned up[2][5];
#pragma unroll
        for (int tp = 0; tp < 2; ++tp) {
            const unsigned* Wr = Wp16 + (size_t)(p0 + tp) * EMB + lane;
#pragma unroll
            for (int j = 0; j < 5; ++j)
                up[tp][j] = (j < 4 || k4ok) ? Wr[64 * j] : 0u;
        }
        float w[4][5];
#pragma unroll
        for (int tp = 0; tp < 2; ++tp)
#pragma unroll
            for (int j = 0; j < 5; ++j) {
                w[2 * tp][j]     = __uint_as_float(up[tp][j] << 16);
                w[2 * tp + 1][j] = __uint_as_float(up[tp][j] & 0xffff0000u);
            }
#pragma unroll
        for (int i = 0; i < 4; ++i) {
            float4 hv = *(const float4*)&rows[wv * 4 + i][d];
#pragma unroll
            for (int j = 0; j < 5; ++j)
                acc[i][j] += hv.x * w[0][j] + hv.y * w[1][j] +
                             hv.z * w[2][j] + hv.w * w[3][j];
        }
    }
#pragma unroll
    for (int i = 0; i < 4; ++i) {
        int li = wv * 4 + i;
        float* hr = h + (size_t)(base + li) * EMB;
        const float* fm = fmean + (size_t)cids[li] * EMB;
#pragma unroll
        for (int j = 0; j < 5; ++j) {
            int k = lane + 64 * j;
            if (j < 4 || k4ok)
                hr[k] = acc[i][j] + b[k] + fm[k];
        }
    }
}

// ---------------- merged edge sort by (a0,a1) combo (9 bins) ----------------
__global__ __launch_bounds__(256) void combo_sort(const int* __restrict__ attr,
                                                  int* __restrict__ esorted,
                                                  int* __restrict__ coffs) {
    __shared__ int sh[9], scur[9];
    int t = threadIdx.x;
    if (t < 9) sh[t] = 0;
    __syncthreads();
    for (int e = t; e < E_EDGE; e += 256)
        atomicAdd(&sh[attr[e * 2] * 3 + attr[e * 2 + 1]], 1);
    __syncthreads();
    if (t == 0) {
        int run = 0;
        for (int c = 0; c < 9; ++c) { scur[c] = run; coffs[c] = run; run += sh[c]; }
        coffs[9] = run;
    }
    __syncthreads();
    for (int e = t; e < E_EDGE; e += 256) {
        int c = attr[e * 2] * 3 + attr[e * 2 + 1];
        int p = atomicAdd(&scur[c], 1);
        esorted[p] = e;
    }
}

// Mc[c] = emb1[c/3] + emb2[c%3]
__global__ void build_mc(const float* __restrict__ emb1, const float* __restrict__ emb2,
                         float* __restrict__ Mc) {
    int c = blockIdx.y;
    int i = blockIdx.x * blockDim.x + threadIdx.x;
    if (i < EMB2)
        Mc[(size_t)c * EMB2 + i] = emb1[(size_t)(c / 3) * EMB2 + i] +
                                   emb2[(size_t)(c % 3) * EMB2 + i];
}

// zero logits (atomic targets) + write constant labels; runs before edge_gemm
__global__ void init_out(float* __restrict__ outp) {
    int i = blockIdx.x * blockDim.x + threadIdx.x;
    if (i < 4 * E_EDGE)
        outp[i] = (i < 2 * E_EDGE) ? 0.f : ((i < 3 * E_EDGE) ? 1.f : 0.f);
}

// ---------------- per-combo fused edge GEMM + partial dots, d-split x3 ----------------
// grid (tile, dchunk, combo); 16 edges/block, 512 thr; thread: 2 edges x 5 cols
// inner d-loop unrolled x2 (40 loads in flight)
__global__ __launch_bounds__(512) void edge_gemm(
    const float* __restrict__ h, const float* __restrict__ Mc,
    const int* __restrict__ eidx, const int* __restrict__ esorted,
    const int* __restrict__ coffs, float* __restrict__ outp) {
    int c     = blockIdx.z;
    int start = coffs[c] + blockIdx.x * 16;
    int end   = coffs[c + 1];
    if (start >= end) return;
    int ne  = min(16, end - start);
    int dlo = blockIdx.y * DCH;

    __shared__ float hs[16][104];   // 104 pad: 416B rows keep b128 16B-aligned
    __shared__ int eids[16], srcs[16], dsts[16], dsts2[16];
    if (threadIdx.x < 16) {
        int li = threadIdx.x;
        int eo = esorted[start + ((li < ne) ? li : 0)];
        eids[li] = eo;
        srcs[li] = eidx[eo];
        dsts[li] = eidx[E_EDGE + eo];
        int ep   = (eo == 0) ? (E_EDGE - 1) : (eo - 1);
        dsts2[li] = eidx[E_EDGE + ep];
    }
    __syncthreads();
    for (int j = threadIdx.x; j < 16 * DCH4; j += 512) {
        int r = j / DCH4, col = j - r * DCH4;
        *(float4*)&hs[r][col * 4] =
            ((const float4*)(h + (size_t)srcs[r] * EMB + dlo))[col];
    }
    __syncthreads();

    int lane = threadIdx.x & 63;
    int wv   = threadIdx.x >> 6;
    bool k4ok = (lane + 256 < EMB);
    const float* M = Mc + (size_t)c * EMB2 + (size_t)dlo * EMB;
    float acc[2][5];
#pragma unroll
    for (int i = 0; i < 2; ++i)
#pragma unroll
        for (int j = 0; j < 5; ++j) acc[i][j] = 0.f;

    int d = 0;
    for (; d + 8 <= DCH; d += 8) {
        float w[8][5];
#pragma unroll
        for (int t = 0; t < 8; ++t) {
            const float* Mr = M + (size_t)(d + t) * EMB + lane;
#pragma unroll
            for (int j = 0; j < 5; ++j)
                w[t][j] = (j < 4 || k4ok) ? Mr[64 * j] : 0.f;
        }
#pragma unroll
        for (int i = 0; i < 2; ++i) {
            float4 hv0 = *(const float4*)&hs[wv * 2 + i][d];
            float4 hv1 = *(const float4*)&hs[wv * 2 + i][d + 4];
#pragma unroll
            for (int j = 0; j < 5; ++j)
                acc[i][j] += hv0.x * w[0][j] + hv0.y * w[1][j] +
                             hv0.z * w[2][j] + hv0.w * w[3][j] +
                             hv1.x * w[4][j] + hv1.y * w[5][j] +
                             hv1.z * w[6][j] + hv1.w * w[7][j];
        }
    }
    {   // tail: 4 remaining d-values (100 = 8*12 + 4)
        float w[4][5];
#pragma unroll
        for (int t = 0; t < 4; ++t) {
            const float* Mr = M + (size_t)(d + t) * EMB + lane;
#pragma unroll
            for (int j = 0; j < 5; ++j)
                w[t][j] = (j < 4 || k4ok) ? Mr[64 * j] : 0.f;
        }
#pragma unroll
        for (int i = 0; i < 2; ++i) {
            float4 hv = *(const float4*)&hs[wv * 2 + i][d];
#pragma unroll
            for (int j = 0; j < 5; ++j)
                acc[i][j] += hv.x * w[0][j] + hv.y * w[1][j] +
                             hv.z * w[2][j] + hv.w * w[3][j];
        }
    }

    // partial dots over this d-chunk's partial v
    float p1[2], p2[2];
#pragma unroll
    for (int i = 0; i < 2; ++i) {
        int li = wv * 2 + i;
        const float* h1 = h + (size_t)dsts[li]  * EMB + lane;
        const float* h2 = h + (size_t)dsts2[li] * EMB + lane;
        float s1 = 0.f, s2 = 0.f;
#pragma unroll
        for (int j = 0; j < 5; ++j) {
            if (j < 4 || k4ok) {
                float a = acc[i][j];
                s1 += a * h1[64 * j];
                s2 += a * h2[64 * j];
            }
        }
        p1[i] = s1; p2[i] = s2;
    }
#pragma unroll
    for (int off = 32; off; off >>= 1) {
#pragma unroll
        for (int i = 0; i < 2; ++i) {
            p1[i] += __shfl_down(p1[i], off);
            p2[i] += __shfl_down(p2[i], off);
        }
    }
    if (lane == 0) {
#pragma unroll
        for (int i = 0; i < 2; ++i) {
            int li = wv * 2 + i;
            if (li < ne) {
                int eo = eids[li];
                atomicAdd(&outp[eo],          p1[i]);
                atomicAdd(&outp[E_EDGE + eo], p2[i]);
            }
        }
    }
}

extern "C" void kernel_launch(void* const* d_in, const int* in_sizes, int n_in,
                              void* d_out, int out_size, void* d_ws, size_t ws_size,
                              hipStream_t stream) {
    const float* out          = (const float*)d_in[0];
    const int*   frag_batch   = (const int*)d_in[1];
    const int*   dangling_idx = (const int*)d_in[2];
    const int*   eidx         = (const int*)d_in[3];
    const int*   attr         = (const int*)d_in[4];
    const float* W            = (const float*)d_in[5];
    const float* b            = (const float*)d_in[6];
    const float* emb1         = (const float*)d_in[7];
    const float* emb2         = (const float*)d_in[8];
    float* o  = (float*)d_out;

    char* p = (char*)d_ws;
    auto alloc = [&](size_t bytes) {
        char* r = p;
        p += (bytes + 255) & ~(size_t)255;
        return (void*)r;
    };
    float*    fmean     = (float*)alloc((size_t)D_DANG * EMB * 4);
    float*    h         = (float*)alloc((size_t)D_DANG * EMB * 4);
    float*    Mc        = (float*)alloc((size_t)9 * EMB2 * 4);
    unsigned* Wp16      = (unsigned*)alloc((size_t)EMBP * EMB * 4);
    int*      hist      = (int*)alloc(F_FRAG * 4);
    int*      offs      = (int*)alloc(F_FRAG * 4);
    int*      cur       = (int*)alloc(F_FRAG * 4);
    int*      remap     = (int*)alloc(F_FRAG * 4);
    int*      node_list = (int*)alloc(N_NODES * 4);
    int*      esorted   = (int*)alloc(E_EDGE * 4);
    int*      coffs     = (int*)alloc(16 * 4);
    int*      n_needed  = (int*)alloc(4);

    init_meta<<<F_FRAG / 256, 256, 0, stream>>>(hist, remap, n_needed);
    mark_needed<<<D_DANG / 256, 256, 0, stream>>>(dangling_idx, frag_batch, remap, n_needed);
    node_hist<<<(N_NODES + 255) / 256, 256, 0, stream>>>(frag_batch, hist);
    scan_hist<<<1, 256, 0, stream>>>(hist, offs, cur);
    scatter_nodes<<<(N_NODES + 255) / 256, 256, 0, stream>>>(frag_batch, remap, cur, node_list);
    pack_w16<<<(EMBP * EMB + 255) / 256, 256, 0, stream>>>(W, Wp16);
    gather_mean<<<F_FRAG / 4, 256, 0, stream>>>(out, remap, hist, offs, node_list, fmean);
    proj_kernel<<<D_DANG / 32, 512, 0, stream>>>(out, dangling_idx, frag_batch, remap,
                                                 Wp16, b, fmean, h);
    combo_sort<<<1, 256, 0, stream>>>(attr, esorted, coffs);
    build_mc<<<dim3((EMB2 + 255) / 256, 9), 256, 0, stream>>>(emb1, emb2, Mc);
    init_out<<<(4 * E_EDGE + 255) / 256, 256, 0, stream>>>(o);
    edge_gemm<<<dim3(64, 3, 9), 512, 0, stream>>>(h, Mc, eidx, esorted, coffs, o);
}

// Round 17
// 146.776 us; speedup vs baseline: 1.0165x; 1.0165x over previous
//
#include <hip/hip_runtime.h>

#define N_NODES 100000
#define F_FRAG  16384
#define D_DANG  8192
#define E_EDGE  4096
#define EMB     300
#define EMB2    90000   // EMB*EMB
#define EMB4    75      // EMB/4
#define DCH     100     // d-chunk for edge gemm (3 chunks)
#define DCH4    25      // DCH/4

// ---------------- init ----------------
__global__ void init_meta(int* hist, int* remap, int* n_needed) {
    int i = blockIdx.x * blockDim.x + threadIdx.x;
    if (i < F_FRAG) { hist[i] = 0; remap[i] = -1; }
    if (i == 0) *n_needed = 0;
}

__global__ void mark_needed(const int* __restrict__ dangling_idx,
                            const int* __restrict__ frag_batch,
                            int* __restrict__ remap, int* __restrict__ n_needed) {
    int i = blockIdx.x * blockDim.x + threadIdx.x;
    if (i >= D_DANG) return;
    int f = frag_batch[dangling_idx[i]];
    if (atomicCAS(&remap[f], -1, -2) == -1)
        remap[f] = atomicAdd(n_needed, 1);
}

// ---------------- counting sort of nodes by fragment ----------------
__global__ void node_hist(const int* __restrict__ frag_batch, int* __restrict__ hist) {
    int i = blockIdx.x * blockDim.x + threadIdx.x;
    if (i < N_NODES) atomicAdd(&hist[frag_batch[i]], 1);
}

__global__ __launch_bounds__(256) void scan_hist(const int* __restrict__ hist,
                                                 int* __restrict__ offs,
                                                 int* __restrict__ cur) {
    __shared__ int part[256];
    __shared__ int pref[257];
    int t = threadIdx.x;
    int base = t * 64;
    int s = 0;
    for (int j = 0; j < 64; ++j) s += hist[base + j];
    part[t] = s;
    __syncthreads();
    if (t == 0) {
        pref[0] = 0;
        for (int i = 0; i < 256; ++i) pref[i + 1] = pref[i] + part[i];
    }
    __syncthreads();
    int run = pref[t];
    for (int j = 0; j < 64; ++j) {
        offs[base + j] = run;
        cur[base + j]  = run;
        run += hist[base + j];
    }
}

__global__ void scatter_nodes(const int* __restrict__ frag_batch,
                              const int* __restrict__ remap,
                              int* __restrict__ cur, int* __restrict__ node_list) {
    int i = blockIdx.x * blockDim.x + threadIdx.x;
    if (i >= N_NODES) return;
    int f = frag_batch[i];
    if (remap[f] < 0) return;
    int p = atomicAdd(&cur[f], 1);
    node_list[p] = i;
}

// one wave per needed fragment, full 300-col row; writes MEAN (compacted)
__global__ __launch_bounds__(256) void gather_mean(
    const float* __restrict__ out, const int* __restrict__ remap,
    const int* __restrict__ hist, const int* __restrict__ offs,
    const int* __restrict__ node_list, float* __restrict__ fmean) {
    int wid = blockIdx.x * 4 + (threadIdx.x >> 6);
    if (wid >= F_FRAG) return;
    int cid = remap[wid];
    if (cid < 0) return;
    int lane = threadIdx.x & 63;
    int cnt = hist[wid], off = offs[wid];
    float acc[5] = {0.f, 0.f, 0.f, 0.f, 0.f};
    int n = 0;
    for (; n + 1 < cnt; n += 2) {
        const float* r0 = out + (size_t)node_list[off + n] * EMB;
        const float* r1 = out + (size_t)node_list[off + n + 1] * EMB;
#pragma unroll
        for (int j = 0; j < 5; ++j) {
            int k = lane + 64 * j;
            if (k < EMB) acc[j] += r0[k] + r1[k];
        }
    }
    if (n < cnt) {
        const float* r0 = out + (size_t)node_list[off + n] * EMB;
#pragma unroll
        for (int j = 0; j < 5; ++j) {
            int k = lane + 64 * j;
            if (k < EMB) acc[j] += r0[k];
        }
    }
    float inv = 1.0f / fmaxf((float)cnt, 1.0f);
#pragma unroll
    for (int j = 0; j < 5; ++j) {
        int k = lane + 64 * j;
        if (k < EMB) fmean[(size_t)cid * EMB + k] = acc[j] * inv;
    }
}

// ---------------- projection: h = out[didx] @ W + b + fmean ----------------
// 32 rows/block, 512 thr = 8 waves; thread: 4 rows x 5 cols; d-loop unrolled x2.
// Halves per-kernel W L1 traffic vs 16-row blocks (wave count halved).
__global__ __launch_bounds__(512) void proj_kernel(
    const float* __restrict__ out, const int* __restrict__ dangling_idx,
    const int* __restrict__ frag_batch, const int* __restrict__ remap,
    const float* __restrict__ W, const float* __restrict__ b,
    const float* __restrict__ fmean, float* __restrict__ h) {
    __shared__ float rows[32][EMB];
    __shared__ int gidx[32], cids[32];
    int base = blockIdx.x * 32;
    if (threadIdx.x < 32) {
        int gi = dangling_idx[base + threadIdx.x];
        gidx[threadIdx.x] = gi;
        cids[threadIdx.x] = remap[frag_batch[gi]];
    }
    __syncthreads();
    {
        float4* dst = (float4*)&rows[0][0];
        for (int j = threadIdx.x; j < 32 * EMB4; j += 512) {
            int r = j / EMB4, col = j - r * EMB4;
            dst[j] = ((const float4*)(out + (size_t)gidx[r] * EMB))[col];
        }
    }
    __syncthreads();
    int lane = threadIdx.x & 63;
    int wv   = threadIdx.x >> 6;   // 0..7, each wave owns 4 rows
    bool k4ok = (lane + 256 < EMB);
    float acc[4][5];
#pragma unroll
    for (int i = 0; i < 4; ++i)
#pragma unroll
        for (int j = 0; j < 5; ++j) acc[i][j] = 0.f;

    int d = 0;
    for (; d + 8 <= EMB; d += 8) {
        float w[8][5];
#pragma unroll
        for (int t = 0; t < 8; ++t) {
            const float* Wr = W + (size_t)(d + t) * EMB + lane;
#pragma unroll
            for (int j = 0; j < 5; ++j)
                w[t][j] = (j < 4 || k4ok) ? Wr[64 * j] : 0.f;
        }
#pragma unroll
        for (int i = 0; i < 4; ++i) {
            float4 hv0 = *(const float4*)&rows[wv * 4 + i][d];
            float4 hv1 = *(const float4*)&rows[wv * 4 + i][d + 4];
#pragma unroll
            for (int j = 0; j < 5; ++j)
                acc[i][j] += hv0.x * w[0][j] + hv0.y * w[1][j] +
                             hv0.z * w[2][j] + hv0.w * w[3][j] +
                             hv1.x * w[4][j] + hv1.y * w[5][j] +
                             hv1.z * w[6][j] + hv1.w * w[7][j];
        }
    }
    {   // tail: 4 remaining d-values (300 = 8*37 + 4)
        float w[4][5];
#pragma unroll
        for (int t = 0; t < 4; ++t) {
            const float* Wr = W + (size_t)(d + t) * EMB + lane;
#pragma unroll
            for (int j = 0; j < 5; ++j)
                w[t][j] = (j < 4 || k4ok) ? Wr[64 * j] : 0.f;
        }
#pragma unroll
        for (int i = 0; i < 4; ++i) {
            float4 hv = *(const float4*)&rows[wv * 4 + i][d];
#pragma unroll
            for (int j = 0; j < 5; ++j)
                acc[i][j] += hv.x * w[0][j] + hv.y * w[1][j] +
                             hv.z * w[2][j] + hv.w * w[3][j];
        }
    }
#pragma unroll
    for (int i = 0; i < 4; ++i) {
        int li = wv * 4 + i;
        float* hr = h + (size_t)(base + li) * EMB;
        const float* fm = fmean + (size_t)cids[li] * EMB;
#pragma unroll
        for (int j = 0; j < 5; ++j) {
            int k = lane + 64 * j;
            if (j < 4 || k4ok)
                hr[k] = acc[i][j] + b[k] + fm[k];
        }
    }
}

// ---------------- merged edge sort by (a0,a1) combo (9 bins) ----------------
__global__ __launch_bounds__(256) void combo_sort(const int* __restrict__ attr,
                                                  int* __restrict__ esorted,
                                                  int* __restrict__ coffs) {
    __shared__ int sh[9], scur[9];
    int t = threadIdx.x;
    if (t < 9) sh[t] = 0;
    __syncthreads();
    for (int e = t; e < E_EDGE; e += 256)
        atomicAdd(&sh[attr[e * 2] * 3 + attr[e * 2 + 1]], 1);
    __syncthreads();
    if (t == 0) {
        int run = 0;
        for (int c = 0; c < 9; ++c) { scur[c] = run; coffs[c] = run; run += sh[c]; }
        coffs[9] = run;
    }
    __syncthreads();
    for (int e = t; e < E_EDGE; e += 256) {
        int c = attr[e * 2] * 3 + attr[e * 2 + 1];
        int p = atomicAdd(&scur[c], 1);
        esorted[p] = e;
    }
}

// Mc[c] = emb1[c/3] + emb2[c%3]
__global__ void build_mc(const float* __restrict__ emb1, const float* __restrict__ emb2,
                         float* __restrict__ Mc) {
    int c = blockIdx.y;
    int i = blockIdx.x * blockDim.x + threadIdx.x;
    if (i < EMB2)
        Mc[(size_t)c * EMB2 + i] = emb1[(size_t)(c / 3) * EMB2 + i] +
                                   emb2[(size_t)(c % 3) * EMB2 + i];
}

// zero logits (atomic targets) + write constant labels; runs before edge_gemm
__global__ void init_out(float* __restrict__ outp) {
    int i = blockIdx.x * blockDim.x + threadIdx.x;
    if (i < 4 * E_EDGE)
        outp[i] = (i < 2 * E_EDGE) ? 0.f : ((i < 3 * E_EDGE) ? 1.f : 0.f);
}

// ---------------- per-combo fused edge GEMM + partial dots, d-split x3 ----------------
// grid (tile, dchunk, combo); 16 edges/block, 512 thr; thread: 2 edges x 5 cols
// inner d-loop unrolled x2 (40 loads in flight)
__global__ __launch_bounds__(512) void edge_gemm(
    const float* __restrict__ h, const float* __restrict__ Mc,
    const int* __restrict__ eidx, const int* __restrict__ esorted,
    const int* __restrict__ coffs, float* __restrict__ outp) {
    int c     = blockIdx.z;
    int start = coffs[c] + blockIdx.x * 16;
    int end   = coffs[c + 1];
    if (start >= end) return;
    int ne  = min(16, end - start);
    int dlo = blockIdx.y * DCH;

    __shared__ float hs[16][104];   // 104 pad: 416B rows keep b128 16B-aligned
    __shared__ int eids[16], srcs[16], dsts[16], dsts2[16];
    if (threadIdx.x < 16) {
        int li = threadIdx.x;
        int eo = esorted[start + ((li < ne) ? li : 0)];
        eids[li] = eo;
        srcs[li] = eidx[eo];
        dsts[li] = eidx[E_EDGE + eo];
        int ep   = (eo == 0) ? (E_EDGE - 1) : (eo - 1);
        dsts2[li] = eidx[E_EDGE + ep];
    }
    __syncthreads();
    for (int j = threadIdx.x; j < 16 * DCH4; j += 512) {
        int r = j / DCH4, col = j - r * DCH4;
        *(float4*)&hs[r][col * 4] =
            ((const float4*)(h + (size_t)srcs[r] * EMB + dlo))[col];
    }
    __syncthreads();

    int lane = threadIdx.x & 63;
    int wv   = threadIdx.x >> 6;
    bool k4ok = (lane + 256 < EMB);
    const float* M = Mc + (size_t)c * EMB2 + (size_t)dlo * EMB;
    float acc[2][5];
#pragma unroll
    for (int i = 0; i < 2; ++i)
#pragma unroll
        for (int j = 0; j < 5; ++j) acc[i][j] = 0.f;

    int d = 0;
    for (; d + 8 <= DCH; d += 8) {
        float w[8][5];
#pragma unroll
        for (int t = 0; t < 8; ++t) {
            const float* Mr = M + (size_t)(d + t) * EMB + lane;
#pragma unroll
            for (int j = 0; j < 5; ++j)
                w[t][j] = (j < 4 || k4ok) ? Mr[64 * j] : 0.f;
        }
#pragma unroll
        for (int i = 0; i < 2; ++i) {
            float4 hv0 = *(const float4*)&hs[wv * 2 + i][d];
            float4 hv1 = *(const float4*)&hs[wv * 2 + i][d + 4];
#pragma unroll
            for (int j = 0; j < 5; ++j)
                acc[i][j] += hv0.x * w[0][j] + hv0.y * w[1][j] +
                             hv0.z * w[2][j] + hv0.w * w[3][j] +
                             hv1.x * w[4][j] + hv1.y * w[5][j] +
                             hv1.z * w[6][j] + hv1.w * w[7][j];
        }
    }
    {   // tail: 4 remaining d-values (100 = 8*12 + 4)
        float w[4][5];
#pragma unroll
        for (int t = 0; t < 4; ++t) {
            const float* Mr = M + (size_t)(d + t) * EMB + lane;
#pragma unroll
            for (int j = 0; j < 5; ++j)
                w[t][j] = (j < 4 || k4ok) ? Mr[64 * j] : 0.f;
        }
#pragma unroll
        for (int i = 0; i < 2; ++i) {
            float4 hv = *(const float4*)&hs[wv * 2 + i][d];
#pragma unroll
            for (int j = 0; j < 5; ++j)
                acc[i][j] += hv.x * w[0][j] + hv.y * w[1][j] +
                             hv.z * w[2][j] + hv.w * w[3][j];
        }
    }

    // partial dots over this d-chunk's partial v
    float p1[2], p2[2];
#pragma unroll
    for (int i = 0; i < 2; ++i) {
        int li = wv * 2 + i;
        const float* h1 = h + (size_t)dsts[li]  * EMB + lane;
        const float* h2 = h + (size_t)dsts2[li] * EMB + lane;
        float s1 = 0.f, s2 = 0.f;
#pragma unroll
        for (int j = 0; j < 5; ++j) {
            if (j < 4 || k4ok) {
                float a = acc[i][j];
                s1 += a * h1[64 * j];
                s2 += a * h2[64 * j];
            }
        }
        p1[i] = s1; p2[i] = s2;
    }
#pragma unroll
    for (int off = 32; off; off >>= 1) {
#pragma unroll
        for (int i = 0; i < 2; ++i) {
            p1[i] += __shfl_down(p1[i], off);
            p2[i] += __shfl_down(p2[i], off);
        }
    }
    if (lane == 0) {
#pragma unroll
        for (int i = 0; i < 2; ++i) {
            int li = wv * 2 + i;
            if (li < ne) {
                int eo = eids[li];
                atomicAdd(&outp[eo],          p1[i]);
                atomicAdd(&outp[E_EDGE + eo], p2[i]);
            }
        }
    }
}

extern "C" void kernel_launch(void* const* d_in, const int* in_sizes, int n_in,
                              void* d_out, int out_size, void* d_ws, size_t ws_size,
                              hipStream_t stream) {
    const float* out          = (const float*)d_in[0];
    const int*   frag_batch   = (const int*)d_in[1];
    const int*   dangling_idx = (const int*)d_in[2];
    const int*   eidx         = (const int*)d_in[3];
    const int*   attr         = (const int*)d_in[4];
    const float* W            = (const float*)d_in[5];
    const float* b            = (const float*)d_in[6];
    const float* emb1         = (const float*)d_in[7];
    const float* emb2         = (const float*)d_in[8];
    float* o  = (float*)d_out;

    char* p = (char*)d_ws;
    auto alloc = [&](size_t bytes) {
        char* r = p;
        p += (bytes + 255) & ~(size_t)255;
        return (void*)r;
    };
    float* fmean     = (float*)alloc((size_t)D_DANG * EMB * 4);
    float* h         = (float*)alloc((size_t)D_DANG * EMB * 4);
    float* Mc        = (float*)alloc((size_t)9 * EMB2 * 4);
    int*   hist      = (int*)alloc(F_FRAG * 4);
    int*   offs      = (int*)alloc(F_FRAG * 4);
    int*   cur       = (int*)alloc(F_FRAG * 4);
    int*   remap     = (int*)alloc(F_FRAG * 4);
    int*   node_list = (int*)alloc(N_NODES * 4);
    int*   esorted   = (int*)alloc(E_EDGE * 4);
    int*   coffs     = (int*)alloc(16 * 4);
    int*   n_needed  = (int*)alloc(4);

    init_meta<<<F_FRAG / 256, 256, 0, stream>>>(hist, remap, n_needed);
    mark_needed<<<D_DANG / 256, 256, 0, stream>>>(dangling_idx, frag_batch, remap, n_needed);
    node_hist<<<(N_NODES + 255) / 256, 256, 0, stream>>>(frag_batch, hist);
    scan_hist<<<1, 256, 0, stream>>>(hist, offs, cur);
    scatter_nodes<<<(N_NODES + 255) / 256, 256, 0, stream>>>(frag_batch, remap, cur, node_list);
    gather_mean<<<F_FRAG / 4, 256, 0, stream>>>(out, remap, hist, offs, node_list, fmean);
    proj_kernel<<<D_DANG / 32, 512, 0, stream>>>(out, dangling_idx, frag_batch, remap,
                                                 W, b, fmean, h);
    combo_sort<<<1, 256, 0, stream>>>(attr, esorted, coffs);
    build_mc<<<dim3((EMB2 + 255) / 256, 9), 256, 0, stream>>>(emb1, emb2, Mc);
    init_out<<<(4 * E_EDGE + 255) / 256, 256, 0, stream>>>(o);
    edge_gemm<<<dim3(64, 3, 9), 512, 0, stream>>>(h, Mc, eidx, esorted, coffs, o);
}